// Round 1
// baseline (528.682 us; speedup 1.0000x reference)
//
#include <hip/hip_runtime.h>

// ---------------------------------------------------------------------------
// BoTNet attention head on MI355X (gfx950).
// Pipeline: conv1x1+BN+ReLU -> qkv conv -> rel-logit precompute ->
//           flash attention (bf16 MFMA, split-K) -> merge ->
//           conv1x1+BN+residual+ReLU -> conv1x1 head.
// ---------------------------------------------------------------------------

typedef __attribute__((ext_vector_type(4))) float f32x4;
typedef __attribute__((ext_vector_type(8))) short s16x8;

#define HW_N 4608
#define EPS 1e-5f
#define QSCALE 0.08838834764831845f  // 128^-0.5

__device__ __forceinline__ unsigned short f2bf(float f) {
  unsigned u = __builtin_bit_cast(unsigned, f);
  u += 0x7fffu + ((u >> 16) & 1u);          // round-to-nearest-even
  return (unsigned short)(u >> 16);
}
__device__ __forceinline__ float bf2f(unsigned short s) {
  return __builtin_bit_cast(float, ((unsigned)s) << 16);
}

// ---------------------------------------------------------------------------
// conv1: h1[64][4608] = relu(bn(w_in @ x)); K=256
// grid 72, block 256. lanes(tx)->p for coalesced stores.
// ---------------------------------------------------------------------------
__global__ __launch_bounds__(256) void conv1_kernel(
    const float* __restrict__ x, const float* __restrict__ w,
    const float* __restrict__ gg, const float* __restrict__ bb,
    const float* __restrict__ mm, const float* __restrict__ vv,
    float* __restrict__ h1)
{
  __shared__ __align__(16) unsigned char smA[16384];  // [cc][oc] f32 swz
  __shared__ __align__(16) unsigned char smB[16384];  // [cc][p]  f32 swz
  const int tid = (int)threadIdx.x;
  const int tx = tid & 15, ty = tid >> 4;
  const int p0 = (int)blockIdx.x * 64;
  float acc[4][4] = {};
  for (int ch = 0; ch < 4; ++ch) {
    __syncthreads();
#pragma unroll
    for (int pass = 0; pass < 4; ++pass) {
      int c4 = tid + pass * 256;
      int oc = c4 >> 4, cc4 = c4 & 15;
      f32x4 a = *(const f32x4*)(w + oc * 256 + ch * 64 + cc4 * 4);
#pragma unroll
      for (int k = 0; k < 4; ++k) {
        int cc = cc4 * 4 + k;
        *(float*)(smA + cc * 256 + ((oc * 4) ^ ((cc & 7) << 4))) = a[k];
      }
      int cc = c4 >> 4, pp4 = c4 & 15;
      f32x4 b = *(const f32x4*)(x + (ch * 64 + cc) * HW_N + p0 + pp4 * 4);
      *(f32x4*)(smB + cc * 256 + ((pp4 * 16) ^ ((cc & 7) << 4))) = b;
    }
    __syncthreads();
#pragma unroll 8
    for (int cc = 0; cc < 64; ++cc) {
      f32x4 av = *(const f32x4*)(smA + cc * 256 + ((ty * 16) ^ ((cc & 7) << 4)));
      f32x4 bv = *(const f32x4*)(smB + cc * 256 + ((tx * 16) ^ ((cc & 7) << 4)));
#pragma unroll
      for (int i = 0; i < 4; ++i)
#pragma unroll
        for (int j = 0; j < 4; ++j) acc[i][j] = fmaf(av[i], bv[j], acc[i][j]);
    }
  }
#pragma unroll
  for (int i = 0; i < 4; ++i) {
    int oc = ty * 4 + i;
    float inv = gg[oc] * rsqrtf(vv[oc] + EPS);
    float bia = bb[oc] - mm[oc] * inv;
    f32x4 o;
#pragma unroll
    for (int j = 0; j < 4; ++j) o[j] = fmaxf(acc[i][j] * inv + bia, 0.f);
    *(f32x4*)(h1 + oc * HW_N + p0 + tx * 4) = o;
  }
}

// ---------------------------------------------------------------------------
// convqkv: qkv[1536][4608] = w_qkv @ h1 ; K=64. Scatter to q(bf16,scaled),
// k(bf16) as [h][p][128]; v(bf16) as [h][128][p] (pre-transposed for PV).
// grid (72, 24), block 256. lanes(tx)->oc so d is lane-contiguous on store.
// ---------------------------------------------------------------------------
__global__ __launch_bounds__(256) void convqkv_kernel(
    const float* __restrict__ h1, const float* __restrict__ w,
    unsigned short* __restrict__ qb, unsigned short* __restrict__ kb,
    unsigned short* __restrict__ vb)
{
  __shared__ __align__(16) unsigned char smA[16384];
  __shared__ __align__(16) unsigned char smB[16384];
  const int tid = (int)threadIdx.x;
  const int tx = tid & 15, ty = tid >> 4;
  const int p0 = (int)blockIdx.x * 64;
  const int o0 = (int)blockIdx.y * 64;
  float acc[4][4] = {};  // [oc][p]
#pragma unroll
  for (int pass = 0; pass < 4; ++pass) {
    int c4 = tid + pass * 256;
    int oc = c4 >> 4, cc4 = c4 & 15;
    f32x4 a = *(const f32x4*)(w + (o0 + oc) * 64 + cc4 * 4);
#pragma unroll
    for (int k = 0; k < 4; ++k) {
      int cc = cc4 * 4 + k;
      *(float*)(smA + cc * 256 + ((oc * 4) ^ ((cc & 7) << 4))) = a[k];
    }
    int cc = c4 >> 4, pp4 = c4 & 15;
    f32x4 b = *(const f32x4*)(h1 + cc * HW_N + p0 + pp4 * 4);
    *(f32x4*)(smB + cc * 256 + ((pp4 * 16) ^ ((cc & 7) << 4))) = b;
  }
  __syncthreads();
#pragma unroll 8
  for (int cc = 0; cc < 64; ++cc) {
    f32x4 av = *(const f32x4*)(smA + cc * 256 + ((tx * 16) ^ ((cc & 7) << 4)));
    f32x4 bv = *(const f32x4*)(smB + cc * 256 + ((ty * 16) ^ ((cc & 7) << 4)));
#pragma unroll
    for (int i = 0; i < 4; ++i)
#pragma unroll
      for (int j = 0; j < 4; ++j) acc[i][j] = fmaf(av[i], bv[j], acc[i][j]);
  }
  const int chunk = o0 >> 9, head = (o0 >> 7) & 3, dbase = o0 & 127;
  if (chunk == 0) {
#pragma unroll
    for (int j = 0; j < 4; ++j) {
      unsigned short pk[4];
#pragma unroll
      for (int i = 0; i < 4; ++i) pk[i] = f2bf(acc[i][j] * QSCALE);
      *(unsigned long long*)(qb + (head * HW_N + p0 + ty * 4 + j) * 128 + dbase + tx * 4) =
          *(unsigned long long*)pk;
    }
  } else if (chunk == 1) {
#pragma unroll
    for (int j = 0; j < 4; ++j) {
      unsigned short pk[4];
#pragma unroll
      for (int i = 0; i < 4; ++i) pk[i] = f2bf(acc[i][j]);
      *(unsigned long long*)(kb + (head * HW_N + p0 + ty * 4 + j) * 128 + dbase + tx * 4) =
          *(unsigned long long*)pk;
    }
  } else {
#pragma unroll
    for (int i = 0; i < 4; ++i) {
      unsigned short pk[4];
#pragma unroll
      for (int j = 0; j < 4; ++j) pk[j] = f2bf(acc[i][j]);
      *(unsigned long long*)(vb + (head * 128 + dbase + tx * 4 + i) * HW_N + p0 + ty * 4) =
          *(unsigned long long*)pk;
    }
  }
}

// ---------------------------------------------------------------------------
// rel-logit precompute: RW[h][p][wk] = q(h,p)·rel_w[wk-wq+95],
//                       RH[h][p][hk] = q(h,p)·rel_h[hk-hq+47]
// ---------------------------------------------------------------------------
__global__ __launch_bounds__(256) void relpre_kernel(
    const unsigned short* __restrict__ qb,
    const float* __restrict__ rel_h, const float* __restrict__ rel_w,
    float* __restrict__ RW, float* __restrict__ RH)
{
  int idx = (int)blockIdx.x * 256 + (int)threadIdx.x;
  if (idx >= 4 * HW_N * 144) return;
  int i = idx % 144;
  int rest = idx / 144;
  int p = rest % HW_N;
  int h = rest / HW_N;
  int wq = p % 96, hq = p / 96;
  const unsigned short* qrow = qb + (h * HW_N + p) * 128;
  const float* rel;
  float* outp;
  if (i < 96) {
    rel = rel_w + (i - wq + 95) * 128;
    outp = RW + (h * HW_N + p) * 96 + i;
  } else {
    int hk = i - 96;
    rel = rel_h + (hk - hq + 47) * 128;
    outp = RH + (h * HW_N + p) * 48 + hk;
  }
  float s = 0.f;
#pragma unroll
  for (int d = 0; d < 128; d += 8) {
    s16x8 qv = *(const s16x8*)(qrow + d);
    f32x4 r0 = *(const f32x4*)(rel + d);
    f32x4 r1 = *(const f32x4*)(rel + d + 4);
#pragma unroll
    for (int e = 0; e < 4; ++e) s = fmaf(bf2f((unsigned short)qv[e]), r0[e], s);
#pragma unroll
    for (int e = 0; e < 4; ++e) s = fmaf(bf2f((unsigned short)qv[4 + e]), r1[e], s);
  }
  *outp = s;
}

// ---------------------------------------------------------------------------
// flash attention. grid (72,4,2) -> XCD-swizzled to (head, khalf, qtile).
// block 256 = 4 waves x 16 queries. key tiles = 48 (image half-rows, so
// hk constant per tile and the RW bias slice is register-resident).
// Split-K (2 halves) with unnormalized O + (m,l) partials.
// ---------------------------------------------------------------------------
__global__ __launch_bounds__(256, 2) void attn_kernel(
    const unsigned short* __restrict__ qb,
    const unsigned short* __restrict__ kbuf,
    const unsigned short* __restrict__ vbuf,
    const float* __restrict__ RW,
    const float* __restrict__ RH,
    float* __restrict__ Opart,
    float* __restrict__ mlbuf)
{
  __shared__ __align__(16) unsigned char sm[36864];
  unsigned char* const smK = sm;          // [48 keys][128 d] bf16, swz (row&7)<<4
  unsigned char* const smV = sm + 12288;  // [128 d][64 keyslots] bf16, swz
  unsigned char* const smP = sm + 28672;  // [4 waves][16 q][64 keyslots] bf16, swz

  const int tid = (int)threadIdx.x;
  const int wv = tid >> 6;
  const int g = (tid >> 4) & 3;
  const int c = tid & 15;
  const int swzc = (c & 7) << 4;

  // XCD swizzle: 8 groups of 72 consecutive linear blocks; group = (h, kh)
  int lin = (int)blockIdx.x + 72 * ((int)blockIdx.y + 4 * (int)blockIdx.z);
  const int grp = lin & 7, mem = lin >> 3;
  const int h = grp >> 1, kh = grp & 1, qt = mem;

  const int qbase = qt * 64 + wv * 16;
  const int woff = wv * 2048;

  {  // zero P (incl. zero-padded keys 48..63) and V pad columns
    s16x8 z = {};
    *(s16x8*)(smP + tid * 16) = z;
    *(s16x8*)(smP + 4096 + tid * 16) = z;
    int d = tid >> 1, k6 = 6 + (tid & 1);
    *(s16x8*)(smV + d * 128 + ((k6 * 16) ^ ((d & 7) << 4))) = z;
  }

  // Q fragments (A-operand: row = lane&15, k = (lane>>4)*8+e)
  s16x8 aq[4];
  {
    const unsigned short* qrow = qb + (h * HW_N + qbase + c) * 128 + g * 8;
#pragma unroll
    for (int kk = 0; kk < 4; ++kk) aq[kk] = *(const s16x8*)(qrow + kk * 32);
  }

  // RW bias registers: per tile-parity, [kb][r]; element = RW[q=g*4+r][wk=par*48+kb*16+c]
  float bw0[3][4], bw1[3][4];
#pragma unroll
  for (int r = 0; r < 4; ++r) {
    const float* rwrow = RW + (h * HW_N + qbase + g * 4 + r) * 96 + c;
#pragma unroll
    for (int kb = 0; kb < 3; ++kb) {
      bw0[kb][r] = rwrow[kb * 16];
      bw1[kb][r] = rwrow[48 + kb * 16];
    }
  }
  const float* rhbase = RH + (h * HW_N + qbase + g * 4) * 48;

  f32x4 o[8];
#pragma unroll
  for (int cb = 0; cb < 8; ++cb) o[cb] = {};
  float mrun[4], lrun[4];
#pragma unroll
  for (int r = 0; r < 4; ++r) { mrun[r] = -1e30f; lrun[r] = 0.f; }

  const unsigned short* kbase = kbuf + (h * HW_N + kh * 2304) * 128;
  const unsigned short* vbase = vbuf + (h * 128) * HW_N + kh * 2304;

  // staging constants
  const int kkey = tid >> 4, kd8 = tid & 15;
  const int swzk = (kkey & 7) << 4;
  const int vd0 = tid / 6, vk0 = tid % 6;
  const int vd1 = (tid + 256) / 6, vk1 = (tid + 256) % 6;
  const int vd2 = (tid + 512) / 6, vk2 = (tid + 512) % 6;

  s16x8 sK0, sK1, sK2, sV0, sV1, sV2;
  {  // prologue: prefetch tile 0
    const unsigned short* kp = kbase + kkey * 128 + kd8 * 8;
    sK0 = *(const s16x8*)(kp);
    sK1 = *(const s16x8*)(kp + 16 * 128);
    sK2 = *(const s16x8*)(kp + 32 * 128);
    sV0 = *(const s16x8*)(vbase + vd0 * HW_N + vk0 * 8);
    sV1 = *(const s16x8*)(vbase + vd1 * HW_N + vk1 * 8);
    sV2 = *(const s16x8*)(vbase + vd2 * HW_N + vk2 * 8);
  }

  for (int t = 0; t < 48; ++t) {
    __syncthreads();  // all waves done reading previous tile
    *(s16x8*)(smK + kkey * 256 + ((kd8 * 16) ^ swzk)) = sK0;
    *(s16x8*)(smK + (kkey + 16) * 256 + ((kd8 * 16) ^ swzk)) = sK1;
    *(s16x8*)(smK + (kkey + 32) * 256 + ((kd8 * 16) ^ swzk)) = sK2;
    *(s16x8*)(smV + vd0 * 128 + ((vk0 * 16) ^ ((vd0 & 7) << 4))) = sV0;
    *(s16x8*)(smV + vd1 * 128 + ((vk1 * 16) ^ ((vd1 & 7) << 4))) = sV1;
    *(s16x8*)(smV + vd2 * 128 + ((vk2 * 16) ^ ((vd2 & 7) << 4))) = sV2;
    if (t < 47) {  // prefetch next tile (latency hides under compute)
      int j0n = (t + 1) * 48;
      const unsigned short* kp = kbase + (j0n + kkey) * 128 + kd8 * 8;
      sK0 = *(const s16x8*)(kp);
      sK1 = *(const s16x8*)(kp + 16 * 128);
      sK2 = *(const s16x8*)(kp + 32 * 128);
      sV0 = *(const s16x8*)(vbase + vd0 * HW_N + j0n + vk0 * 8);
      sV1 = *(const s16x8*)(vbase + vd1 * HW_N + j0n + vk1 * 8);
      sV2 = *(const s16x8*)(vbase + vd2 * HW_N + j0n + vk2 * 8);
    }
    const int hk = kh * 24 + (t >> 1);
    float rh_[4];
#pragma unroll
    for (int r = 0; r < 4; ++r) rh_[r] = rhbase[r * 48 + hk];
    __syncthreads();  // staged tile visible

    // ---- S = Q K^T (16q x 48k) ----
    f32x4 s0 = {}, s1 = {}, s2 = {};
#pragma unroll
    for (int kk = 0; kk < 4; ++kk) {
      const int inr = kk * 64 + g * 16;
      s16x8 b0 = *(const s16x8*)(smK + c * 256 + (inr ^ swzc));
      s16x8 b1 = *(const s16x8*)(smK + (16 + c) * 256 + (inr ^ swzc));
      s16x8 b2 = *(const s16x8*)(smK + (32 + c) * 256 + (inr ^ swzc));
      s0 = __builtin_amdgcn_mfma_f32_16x16x32_bf16(aq[kk], b0, s0, 0, 0, 0);
      s1 = __builtin_amdgcn_mfma_f32_16x16x32_bf16(aq[kk], b1, s1, 0, 0, 0);
      s2 = __builtin_amdgcn_mfma_f32_16x16x32_bf16(aq[kk], b2, s2, 0, 0, 0);
    }

    // ---- bias + online softmax (row reduce across 16 lanes of group) ----
    const bool par = (t & 1) != 0;
#pragma unroll
    for (int r = 0; r < 4; ++r) {
      float x0 = s0[r] + (par ? bw1[0][r] : bw0[0][r]) + rh_[r];
      float x1 = s1[r] + (par ? bw1[1][r] : bw0[1][r]) + rh_[r];
      float x2 = s2[r] + (par ? bw1[2][r] : bw0[2][r]) + rh_[r];
      float tm = fmaxf(fmaxf(x0, x1), x2);
      tm = fmaxf(tm, __shfl_xor(tm, 1, 16));
      tm = fmaxf(tm, __shfl_xor(tm, 2, 16));
      tm = fmaxf(tm, __shfl_xor(tm, 4, 16));
      tm = fmaxf(tm, __shfl_xor(tm, 8, 16));
      float mn = fmaxf(mrun[r], tm);
      float fac = __expf(mrun[r] - mn);
      mrun[r] = mn;
      float p0 = __expf(x0 - mn);
      float p1 = __expf(x1 - mn);
      float p2 = __expf(x2 - mn);
      float rs = p0 + p1 + p2;
      rs += __shfl_xor(rs, 1, 16);
      rs += __shfl_xor(rs, 2, 16);
      rs += __shfl_xor(rs, 4, 16);
      rs += __shfl_xor(rs, 8, 16);
      lrun[r] = lrun[r] * fac + rs;
#pragma unroll
      for (int cb = 0; cb < 8; ++cb) o[cb][r] *= fac;
      const int q_ = g * 4 + r;
      unsigned char* prow = smP + woff + q_ * 128;
      const int swzq = (q_ & 7) << 4;
      *(unsigned short*)(prow + ((c * 2) ^ swzq)) = f2bf(p0);
      *(unsigned short*)(prow + ((32 + c * 2) ^ swzq)) = f2bf(p1);
      *(unsigned short*)(prow + ((64 + c * 2) ^ swzq)) = f2bf(p2);
    }

    // ---- O += P V ----
    s16x8 pa0 = *(const s16x8*)(smP + woff + c * 128 + ((g * 16) ^ swzc));
    s16x8 pa1 = *(const s16x8*)(smP + woff + c * 128 + ((64 + g * 16) ^ swzc));
#pragma unroll
    for (int cb = 0; cb < 8; ++cb) {
      const unsigned char* vrow = smV + (cb * 16 + c) * 128;
      s16x8 v0 = *(const s16x8*)(vrow + ((g * 16) ^ swzc));
      s16x8 v1 = *(const s16x8*)(vrow + ((64 + g * 16) ^ swzc));
      o[cb] = __builtin_amdgcn_mfma_f32_16x16x32_bf16(pa0, v0, o[cb], 0, 0, 0);
      o[cb] = __builtin_amdgcn_mfma_f32_16x16x32_bf16(pa1, v1, o[cb], 0, 0, 0);
    }
  }

  const int pb = (kh * 4 + h) * HW_N;
#pragma unroll
  for (int r = 0; r < 4; ++r) {
    const int p = qbase + g * 4 + r;
    float* orow = Opart + (pb + p) * 128 + c;
#pragma unroll
    for (int cb = 0; cb < 8; ++cb) orow[cb * 16] = o[cb][r];
    if (c == 0) {
      mlbuf[(pb + p) * 2 + 0] = mrun[r];
      mlbuf[(pb + p) * 2 + 1] = lrun[r];
    }
  }
}

// ---------------------------------------------------------------------------
// merge split-K partials -> out_att[p][512] (p-major so conv stage is coalesced)
// ---------------------------------------------------------------------------
__global__ __launch_bounds__(256) void merge_kernel(
    const float* __restrict__ Opart, const float* __restrict__ mlbuf,
    float* __restrict__ oatt)
{
  int idx = (int)blockIdx.x * 256 + (int)threadIdx.x;  // 4*4608*32
  int d4 = idx & 31;
  int rest = idx >> 5;
  int p = rest % HW_N;
  int h = rest / HW_N;
  int i0 = h * HW_N + p;
  int i1 = (4 + h) * HW_N + p;
  float m0 = mlbuf[i0 * 2], l0 = mlbuf[i0 * 2 + 1];
  float m1 = mlbuf[i1 * 2], l1 = mlbuf[i1 * 2 + 1];
  float M = fmaxf(m0, m1);
  float a0 = __expf(m0 - M), a1 = __expf(m1 - M);
  float rd = 1.f / (a0 * l0 + a1 * l1);
  f32x4 O0 = *(const f32x4*)(Opart + i0 * 128 + d4 * 4);
  f32x4 O1 = *(const f32x4*)(Opart + i1 * 128 + d4 * 4);
  f32x4 res;
#pragma unroll
  for (int j = 0; j < 4; ++j) res[j] = (a0 * O0[j] + a1 * O1[j]) * rd;
  *(f32x4*)(oatt + p * 512 + h * 128 + d4 * 4) = res;
}

// ---------------------------------------------------------------------------
// convout: fm[256][4608] = relu(bn(w_out @ out_att^T) + x); K=512, B from [p][c]
// grid (72, 4), block 256
// ---------------------------------------------------------------------------
__global__ __launch_bounds__(256) void convout_kernel(
    const float* __restrict__ oatt, const float* __restrict__ w,
    const float* __restrict__ gg, const float* __restrict__ bb,
    const float* __restrict__ mm, const float* __restrict__ vv,
    const float* __restrict__ x, float* __restrict__ fm)
{
  __shared__ __align__(16) unsigned char smA[16384];
  __shared__ __align__(16) unsigned char smB[16384];
  const int tid = (int)threadIdx.x;
  const int tx = tid & 15, ty = tid >> 4;
  const int p0 = (int)blockIdx.x * 64;
  const int o0 = (int)blockIdx.y * 64;
  float acc[4][4] = {};  // [oc][p]
  for (int ch = 0; ch < 8; ++ch) {
    __syncthreads();
#pragma unroll
    for (int pass = 0; pass < 4; ++pass) {
      int c4 = tid + pass * 256;
      int oc = c4 >> 4, cc4 = c4 & 15;
      f32x4 a = *(const f32x4*)(w + (o0 + oc) * 512 + ch * 64 + cc4 * 4);
#pragma unroll
      for (int k = 0; k < 4; ++k) {
        int cc = cc4 * 4 + k;
        *(float*)(smA + cc * 256 + ((oc * 4) ^ ((cc & 7) << 4))) = a[k];
      }
      int pl = c4 >> 4, cc4b = c4 & 15;
      f32x4 b = *(const f32x4*)(oatt + (p0 + pl) * 512 + ch * 64 + cc4b * 4);
#pragma unroll
      for (int k = 0; k < 4; ++k) {
        int cc = cc4b * 4 + k;
        *(float*)(smB + cc * 256 + ((pl * 4) ^ ((cc & 7) << 4))) = b[k];
      }
    }
    __syncthreads();
#pragma unroll 8
    for (int cc = 0; cc < 64; ++cc) {
      f32x4 av = *(const f32x4*)(smA + cc * 256 + ((ty * 16) ^ ((cc & 7) << 4)));
      f32x4 bv = *(const f32x4*)(smB + cc * 256 + ((tx * 16) ^ ((cc & 7) << 4)));
#pragma unroll
      for (int i = 0; i < 4; ++i)
#pragma unroll
        for (int j = 0; j < 4; ++j) acc[i][j] = fmaf(av[i], bv[j], acc[i][j]);
    }
  }
#pragma unroll
  for (int i = 0; i < 4; ++i) {
    int oc = o0 + ty * 4 + i;
    float inv = gg[oc] * rsqrtf(vv[oc] + EPS);
    float bia = bb[oc] - mm[oc] * inv;
    f32x4 xr = *(const f32x4*)(x + oc * HW_N + p0 + tx * 4);
    f32x4 o;
#pragma unroll
    for (int j = 0; j < 4; ++j) o[j] = fmaxf(acc[i][j] * inv + bia + xr[j], 0.f);
    *(f32x4*)(fm + oc * HW_N + p0 + tx * 4) = o;
  }
}

// ---------------------------------------------------------------------------
// convhead: out[19][4608] = w_head @ fm + b_head; K=256. grid 72, block 256
// ---------------------------------------------------------------------------
__global__ __launch_bounds__(256) void convhead_kernel(
    const float* __restrict__ fm, const float* __restrict__ w,
    const float* __restrict__ bh, float* __restrict__ outp)
{
  __shared__ __align__(16) unsigned char smA[16384];
  __shared__ __align__(16) unsigned char smB[16384];
  const int tid = (int)threadIdx.x;
  const int tx = tid & 15, ty = tid >> 4;
  const int p0 = (int)blockIdx.x * 64;
  float acc[4][4] = {};
  for (int ch = 0; ch < 4; ++ch) {
    __syncthreads();
#pragma unroll
    for (int pass = 0; pass < 4; ++pass) {
      int c4 = tid + pass * 256;
      int oc = c4 >> 4, cc4 = c4 & 15;
      f32x4 a = {};
      if (oc < 19) a = *(const f32x4*)(w + oc * 256 + ch * 64 + cc4 * 4);
#pragma unroll
      for (int k = 0; k < 4; ++k) {
        int cc = cc4 * 4 + k;
        *(float*)(smA + cc * 256 + ((oc * 4) ^ ((cc & 7) << 4))) = a[k];
      }
      int cc = c4 >> 4, pp4 = c4 & 15;
      f32x4 b = *(const f32x4*)(fm + (ch * 64 + cc) * HW_N + p0 + pp4 * 4);
      *(f32x4*)(smB + cc * 256 + ((pp4 * 16) ^ ((cc & 7) << 4))) = b;
    }
    __syncthreads();
#pragma unroll 8
    for (int cc = 0; cc < 64; ++cc) {
      f32x4 av = *(const f32x4*)(smA + cc * 256 + ((ty * 16) ^ ((cc & 7) << 4)));
      f32x4 bv = *(const f32x4*)(smB + cc * 256 + ((tx * 16) ^ ((cc & 7) << 4)));
#pragma unroll
      for (int i = 0; i < 4; ++i)
#pragma unroll
        for (int j = 0; j < 4; ++j) acc[i][j] = fmaf(av[i], bv[j], acc[i][j]);
    }
  }
#pragma unroll
  for (int i = 0; i < 4; ++i) {
    int oc = ty * 4 + i;
    if (oc < 19) {
      f32x4 o;
#pragma unroll
      for (int j = 0; j < 4; ++j) o[j] = acc[i][j] + bh[oc];
      *(f32x4*)(outp + oc * HW_N + p0 + tx * 4) = o;
    }
  }
}

// ---------------------------------------------------------------------------
extern "C" void kernel_launch(void* const* d_in, const int* in_sizes, int n_in,
                              void* d_out, int out_size, void* d_ws, size_t ws_size,
                              hipStream_t stream)
{
  const float* x     = (const float*)d_in[0];
  const float* w_in  = (const float*)d_in[1];
  const float* bn1_g = (const float*)d_in[2];
  const float* bn1_b = (const float*)d_in[3];
  const float* bn1_m = (const float*)d_in[4];
  const float* bn1_v = (const float*)d_in[5];
  const float* w_qkv = (const float*)d_in[6];
  const float* rel_h = (const float*)d_in[7];
  const float* rel_w = (const float*)d_in[8];
  const float* w_out = (const float*)d_in[9];
  const float* bn2_g = (const float*)d_in[10];
  const float* bn2_b = (const float*)d_in[11];
  const float* bn2_m = (const float*)d_in[12];
  const float* bn2_v = (const float*)d_in[13];
  const float* w_hd  = (const float*)d_in[14];
  const float* b_hd  = (const float*)d_in[15];

  char* ws = (char*)d_ws;
  float*          h1    = (float*)(ws + 0);                   // 1,179,648 B
  unsigned short* qb    = (unsigned short*)(ws + 1179648);    // 4,718,592 B
  unsigned short* kb    = (unsigned short*)(ws + 5898240);    // 4,718,592 B
  unsigned short* vb    = (unsigned short*)(ws + 10616832);   // 4,718,592 B
  float*          RW    = (float*)(ws + 15335424);            // 7,077,888 B
  float*          RH    = (float*)(ws + 22413312);            // 3,538,944 B
  float*          Opart = (float*)(ws + 25952256);            // 18,874,368 B
  float*          mlb   = (float*)(ws + 44826624);            // 294,912 B
  float*          oatt  = (float*)(ws + 45121536);            // 9,437,184 B
  float*          fm    = (float*)(ws + 54558720);            // 4,718,592 B

  conv1_kernel<<<72, 256, 0, stream>>>(x, w_in, bn1_g, bn1_b, bn1_m, bn1_v, h1);
  convqkv_kernel<<<dim3(72, 24), 256, 0, stream>>>(h1, w_qkv, qb, kb, vb);
  relpre_kernel<<<10368, 256, 0, stream>>>(qb, rel_h, rel_w, RW, RH);
  attn_kernel<<<dim3(72, 4, 2), 256, 0, stream>>>(qb, kb, vb, RW, RH, Opart, mlb);
  merge_kernel<<<2304, 256, 0, stream>>>(Opart, mlb, oatt);
  convout_kernel<<<dim3(72, 4), 256, 0, stream>>>(oatt, w_out, bn2_g, bn2_b, bn2_m,
                                                  bn2_v, x, fm);
  convhead_kernel<<<72, 256, 0, stream>>>(fm, w_hd, b_hd, (float*)d_out);
}

// Round 2
// 307.167 us; speedup vs baseline: 1.7212x; 1.7212x over previous
//
#include <hip/hip_runtime.h>

// ---------------------------------------------------------------------------
// BoTNet attention head on MI355X (gfx950).
// Pipeline: conv1x1+BN+ReLU -> qkv conv -> rel-logit MFMA precompute ->
//           flash attention (bf16 MFMA, split-K=4, defer-max) -> merge ->
//           conv1x1+BN+residual+ReLU -> conv1x1 head.
// ---------------------------------------------------------------------------

typedef __attribute__((ext_vector_type(4))) float f32x4;
typedef __attribute__((ext_vector_type(8))) short s16x8;
typedef __attribute__((ext_vector_type(4))) unsigned short u16x4;

#define HW_N 4608
#define EPS 1e-5f
#define QSCALE 0.08838834764831845f  // 128^-0.5

__device__ __forceinline__ unsigned short f2bf(float f) {
  unsigned u = __builtin_bit_cast(unsigned, f);
  u += 0x7fffu + ((u >> 16) & 1u);          // round-to-nearest-even
  return (unsigned short)(u >> 16);
}
__device__ __forceinline__ float bf2f(unsigned short s) {
  return __builtin_bit_cast(float, ((unsigned)s) << 16);
}

// ---------------------------------------------------------------------------
// conv1: h1[64][4608] = relu(bn(w_in @ x)); K=256
// ---------------------------------------------------------------------------
__global__ __launch_bounds__(256) void conv1_kernel(
    const float* __restrict__ x, const float* __restrict__ w,
    const float* __restrict__ gg, const float* __restrict__ bb,
    const float* __restrict__ mm, const float* __restrict__ vv,
    float* __restrict__ h1)
{
  __shared__ __align__(16) unsigned char smA[16384];  // [cc][oc] f32 swz
  __shared__ __align__(16) unsigned char smB[16384];  // [cc][p]  f32 swz
  const int tid = (int)threadIdx.x;
  const int tx = tid & 15, ty = tid >> 4;
  const int p0 = (int)blockIdx.x * 64;
  float acc[4][4] = {};
  for (int ch = 0; ch < 4; ++ch) {
    __syncthreads();
#pragma unroll
    for (int pass = 0; pass < 4; ++pass) {
      int c4 = tid + pass * 256;
      int oc = c4 >> 4, cc4 = c4 & 15;
      f32x4 a = *(const f32x4*)(w + oc * 256 + ch * 64 + cc4 * 4);
#pragma unroll
      for (int k = 0; k < 4; ++k) {
        int cc = cc4 * 4 + k;
        *(float*)(smA + cc * 256 + ((oc * 4) ^ ((cc & 7) << 4))) = a[k];
      }
      int cc = c4 >> 4, pp4 = c4 & 15;
      f32x4 b = *(const f32x4*)(x + (ch * 64 + cc) * HW_N + p0 + pp4 * 4);
      *(f32x4*)(smB + cc * 256 + ((pp4 * 16) ^ ((cc & 7) << 4))) = b;
    }
    __syncthreads();
#pragma unroll 8
    for (int cc = 0; cc < 64; ++cc) {
      f32x4 av = *(const f32x4*)(smA + cc * 256 + ((ty * 16) ^ ((cc & 7) << 4)));
      f32x4 bv = *(const f32x4*)(smB + cc * 256 + ((tx * 16) ^ ((cc & 7) << 4)));
#pragma unroll
      for (int i = 0; i < 4; ++i)
#pragma unroll
        for (int j = 0; j < 4; ++j) acc[i][j] = fmaf(av[i], bv[j], acc[i][j]);
    }
  }
#pragma unroll
  for (int i = 0; i < 4; ++i) {
    int oc = ty * 4 + i;
    float inv = gg[oc] * rsqrtf(vv[oc] + EPS);
    float bia = bb[oc] - mm[oc] * inv;
    f32x4 o;
#pragma unroll
    for (int j = 0; j < 4; ++j) o[j] = fmaxf(acc[i][j] * inv + bia, 0.f);
    *(f32x4*)(h1 + oc * HW_N + p0 + tx * 4) = o;
  }
}

// ---------------------------------------------------------------------------
// convqkv: qkv[1536][4608] = w_qkv @ h1 ; K=64. Scatter to q(bf16,scaled),
// k(bf16) as [h][p][128]; v(bf16) as [h][128][p] (pre-transposed for PV).
// ---------------------------------------------------------------------------
__global__ __launch_bounds__(256) void convqkv_kernel(
    const float* __restrict__ h1, const float* __restrict__ w,
    unsigned short* __restrict__ qb, unsigned short* __restrict__ kb,
    unsigned short* __restrict__ vb)
{
  __shared__ __align__(16) unsigned char smA[16384];
  __shared__ __align__(16) unsigned char smB[16384];
  const int tid = (int)threadIdx.x;
  const int tx = tid & 15, ty = tid >> 4;
  const int p0 = (int)blockIdx.x * 64;
  const int o0 = (int)blockIdx.y * 64;
  float acc[4][4] = {};  // [oc][p]
#pragma unroll
  for (int pass = 0; pass < 4; ++pass) {
    int c4 = tid + pass * 256;
    int oc = c4 >> 4, cc4 = c4 & 15;
    f32x4 a = *(const f32x4*)(w + (o0 + oc) * 64 + cc4 * 4);
#pragma unroll
    for (int k = 0; k < 4; ++k) {
      int cc = cc4 * 4 + k;
      *(float*)(smA + cc * 256 + ((oc * 4) ^ ((cc & 7) << 4))) = a[k];
    }
    int cc = c4 >> 4, pp4 = c4 & 15;
    f32x4 b = *(const f32x4*)(h1 + cc * HW_N + p0 + pp4 * 4);
    *(f32x4*)(smB + cc * 256 + ((pp4 * 16) ^ ((cc & 7) << 4))) = b;
  }
  __syncthreads();
#pragma unroll 8
  for (int cc = 0; cc < 64; ++cc) {
    f32x4 av = *(const f32x4*)(smA + cc * 256 + ((tx * 16) ^ ((cc & 7) << 4)));
    f32x4 bv = *(const f32x4*)(smB + cc * 256 + ((ty * 16) ^ ((cc & 7) << 4)));
#pragma unroll
    for (int i = 0; i < 4; ++i)
#pragma unroll
      for (int j = 0; j < 4; ++j) acc[i][j] = fmaf(av[i], bv[j], acc[i][j]);
  }
  const int chunk = o0 >> 9, head = (o0 >> 7) & 3, dbase = o0 & 127;
  if (chunk == 0) {
#pragma unroll
    for (int j = 0; j < 4; ++j) {
      unsigned short pk[4];
#pragma unroll
      for (int i = 0; i < 4; ++i) pk[i] = f2bf(acc[i][j] * QSCALE);
      *(unsigned long long*)(qb + (head * HW_N + p0 + ty * 4 + j) * 128 + dbase + tx * 4) =
          *(unsigned long long*)pk;
    }
  } else if (chunk == 1) {
#pragma unroll
    for (int j = 0; j < 4; ++j) {
      unsigned short pk[4];
#pragma unroll
      for (int i = 0; i < 4; ++i) pk[i] = f2bf(acc[i][j]);
      *(unsigned long long*)(kb + (head * HW_N + p0 + ty * 4 + j) * 128 + dbase + tx * 4) =
          *(unsigned long long*)pk;
    }
  } else {
#pragma unroll
    for (int i = 0; i < 4; ++i) {
      unsigned short pk[4];
#pragma unroll
      for (int j = 0; j < 4; ++j) pk[j] = f2bf(acc[i][j]);
      *(unsigned long long*)(vb + (head * 128 + dbase + tx * 4 + i) * HW_N + p0 + ty * 4) =
          *(unsigned long long*)pk;
    }
  }
}

// ---------------------------------------------------------------------------
// relpre via MFMA. mode 0 (per (wq=bx, h)): C[48 hq][96 wk] = Q·rel_w-slice
//                  mode 1 (per (hq=bx, h)): C[96 wq][48 hk] = Q·rel_h-slice
// Writes RW[(h*HW+p)*96+wk] / RH[(h*HW+p)*48+hk], p = hq*96+wq.
// ---------------------------------------------------------------------------
__global__ __launch_bounds__(256) void relpre_mfma(
    const unsigned short* __restrict__ qb, const float* __restrict__ rel,
    float* __restrict__ outp, int mode)
{
  __shared__ __align__(16) unsigned char sm[36864];  // Q rows then rel rows
  const int bx = (int)blockIdx.x, h = (int)blockIdx.y;
  const int tid = (int)threadIdx.x;
  const int wv = tid >> 6, g = (tid >> 4) & 3, c = tid & 15;
  const int NA = mode ? 96 : 48;
  const int NB = mode ? 48 : 96;
  const int TC = NB >> 4;
  const int roff = mode ? (47 - bx) : (95 - bx);
  unsigned char* const smQ = sm;
  unsigned char* const smR = sm + NA * 256;

  for (int ch = tid; ch < (NA + NB) * 16; ch += 256) {
    if (ch < NA * 16) {
      int i = ch >> 4, d8 = ch & 15;
      int p = mode ? (bx * 96 + i) : (i * 96 + bx);
      s16x8 v = *(const s16x8*)(qb + ((size_t)h * HW_N + p) * 128 + d8 * 8);
      *(s16x8*)(smQ + i * 256 + ((d8 * 16) ^ ((i & 7) << 4))) = v;
    } else {
      int c2 = ch - NA * 16;
      int j = c2 >> 4, d8 = c2 & 15;
      const float* rp = rel + (roff + j) * 128 + d8 * 8;
      f32x4 r0 = *(const f32x4*)(rp);
      f32x4 r1 = *(const f32x4*)(rp + 4);
      s16x8 pk;
#pragma unroll
      for (int e = 0; e < 4; ++e) {
        pk[e] = (short)f2bf(r0[e]);
        pk[4 + e] = (short)f2bf(r1[e]);
      }
      *(s16x8*)(smR + j * 256 + ((d8 * 16) ^ ((j & 7) << 4))) = pk;
    }
  }
  __syncthreads();

  const int swzc = (c & 7) << 4;
  for (int tile = wv; tile < 18; tile += 4) {
    const int tr = tile / TC, tc = tile % TC;
    f32x4 acc = {};
#pragma unroll
    for (int kk = 0; kk < 4; ++kk) {
      const int koff = (kk * 64 + g * 16) ^ swzc;
      s16x8 a = *(const s16x8*)(smQ + (tr * 16 + c) * 256 + koff);
      s16x8 b = *(const s16x8*)(smR + (tc * 16 + c) * 256 + koff);
      acc = __builtin_amdgcn_mfma_f32_16x16x32_bf16(a, b, acc, 0, 0, 0);
    }
#pragma unroll
    for (int j = 0; j < 4; ++j) {
      int i = tr * 16 + g * 4 + j;   // row (hq for mode0 / wq for mode1)
      int n = tc * 16 + c;           // col (wk / hk)
      if (mode == 0)
        outp[((size_t)h * HW_N + i * 96 + bx) * 96 + n] = acc[j];
      else
        outp[((size_t)h * HW_N + bx * 96 + i) * 48 + n] = acc[j];
    }
  }
}

// ---------------------------------------------------------------------------
// flash attention. grid (72,4,4): 16 (h,kh) groups x 72 q-tiles, XCD-grouped.
// block 256 = 4 waves x 16 queries. key tiles = 48 image half-rows.
// Split-K=4, unnormalized O (bf16) + (m,l) partials, defer-max THR=8.
// ---------------------------------------------------------------------------
__global__ __launch_bounds__(256, 2) void attn_kernel(
    const unsigned short* __restrict__ qb,
    const unsigned short* __restrict__ kbuf,
    const unsigned short* __restrict__ vbuf,
    const float* __restrict__ RW,
    const float* __restrict__ RH,
    unsigned short* __restrict__ Opart,
    float* __restrict__ mlbuf)
{
  __shared__ __align__(16) unsigned char sm[36864];
  unsigned char* const smK = sm;          // [48 keys][128 d] bf16, swz (row&7)<<4
  unsigned char* const smV = sm + 12288;  // [128 d][64 keyslots] bf16, swz
  unsigned char* const smP = sm + 28672;  // [4 waves][16 q][64 keyslots] bf16

  const int tid = (int)threadIdx.x;
  const int wv = tid >> 6;
  const int g = (tid >> 4) & 3;
  const int c = tid & 15;
  const int swzc = (c & 7) << 4;
  // P swizzle: group-varying bits into 32B-window bits -> conflict-free writes
  const int pswz_c = ((c >> 2) << 5) | ((c & 1) << 4);

  // XCD swizzle: 16 groups of 72 consecutive linear blocks; group = (h, kh)
  int lin = (int)blockIdx.x + 72 * ((int)blockIdx.y + 4 * (int)blockIdx.z);
  const int grp = lin & 15, mem = lin >> 4;
  const int h = grp & 3, kh = grp >> 2, qt = mem;

  const int qbase = qt * 64 + wv * 16;
  const int woff = wv * 2048;

  {  // zero P (incl. zero-padded keys 48..63) and V pad columns
    s16x8 z = {};
    *(s16x8*)(smP + tid * 16) = z;
    *(s16x8*)(smP + 4096 + tid * 16) = z;
    int d = tid >> 1, k6 = 6 + (tid & 1);
    *(s16x8*)(smV + d * 128 + ((k6 * 16) ^ ((d & 7) << 4))) = z;
  }

  // Q fragments (A-operand: row = lane&15, k = (lane>>4)*8+e)
  s16x8 aq[4];
  {
    const unsigned short* qrow = qb + ((size_t)h * HW_N + qbase + c) * 128 + g * 8;
#pragma unroll
    for (int kk = 0; kk < 4; ++kk) aq[kk] = *(const s16x8*)(qrow + kk * 32);
  }

  // RW bias registers: per tile-parity [kb][r]; elem = RW[q=g*4+r][wk=par*48+kb*16+c]
  float bw0[3][4], bw1[3][4];
#pragma unroll
  for (int r = 0; r < 4; ++r) {
    const float* rwrow = RW + ((size_t)h * HW_N + qbase + g * 4 + r) * 96 + c;
#pragma unroll
    for (int kb = 0; kb < 3; ++kb) {
      bw0[kb][r] = rwrow[kb * 16];
      bw1[kb][r] = rwrow[48 + kb * 16];
    }
  }
  // RH: 12 hk values of this kh-quarter live in lanes 0..11 of each group
  float rh_pre[4];
#pragma unroll
  for (int r = 0; r < 4; ++r)
    rh_pre[r] = (c < 12)
        ? RH[((size_t)h * HW_N + qbase + g * 4 + r) * 48 + kh * 12 + c] : 0.f;

  f32x4 o[8];
#pragma unroll
  for (int cb = 0; cb < 8; ++cb) o[cb] = {};
  float mrun[4], lrun[4];
#pragma unroll
  for (int r = 0; r < 4; ++r) { mrun[r] = -1e30f; lrun[r] = 0.f; }

  const unsigned short* kbase = kbuf + ((size_t)h * HW_N + kh * 1152) * 128;
  const unsigned short* vbase = vbuf + (size_t)h * 128 * HW_N + kh * 1152;

  // staging constants
  const int kkey = tid >> 4, kd8 = tid & 15;
  const int swzk = (kkey & 7) << 4;
  const int vd0 = tid / 6, vk0 = tid % 6;
  const int vd1 = (tid + 256) / 6, vk1 = (tid + 256) % 6;
  const int vd2 = (tid + 512) / 6, vk2 = (tid + 512) % 6;

  s16x8 sK0, sK1, sK2, sV0, sV1, sV2;
  {  // prologue: prefetch tile 0
    const unsigned short* kp = kbase + kkey * 128 + kd8 * 8;
    sK0 = *(const s16x8*)(kp);
    sK1 = *(const s16x8*)(kp + 16 * 128);
    sK2 = *(const s16x8*)(kp + 32 * 128);
    sV0 = *(const s16x8*)(vbase + vd0 * HW_N + vk0 * 8);
    sV1 = *(const s16x8*)(vbase + vd1 * HW_N + vk1 * 8);
    sV2 = *(const s16x8*)(vbase + vd2 * HW_N + vk2 * 8);
  }

  for (int t = 0; t < 24; ++t) {
    __syncthreads();  // all waves done reading previous tile
    *(s16x8*)(smK + kkey * 256 + ((kd8 * 16) ^ swzk)) = sK0;
    *(s16x8*)(smK + (kkey + 16) * 256 + ((kd8 * 16) ^ swzk)) = sK1;
    *(s16x8*)(smK + (kkey + 32) * 256 + ((kd8 * 16) ^ swzk)) = sK2;
    *(s16x8*)(smV + vd0 * 128 + ((vk0 * 16) ^ ((vd0 & 7) << 4))) = sV0;
    *(s16x8*)(smV + vd1 * 128 + ((vk1 * 16) ^ ((vd1 & 7) << 4))) = sV1;
    *(s16x8*)(smV + vd2 * 128 + ((vk2 * 16) ^ ((vd2 & 7) << 4))) = sV2;
    if (t < 23) {  // prefetch next tile (latency hides under compute)
      int j0n = (t + 1) * 48;
      const unsigned short* kp = kbase + (j0n + kkey) * 128 + kd8 * 8;
      sK0 = *(const s16x8*)(kp);
      sK1 = *(const s16x8*)(kp + 16 * 128);
      sK2 = *(const s16x8*)(kp + 32 * 128);
      sV0 = *(const s16x8*)(vbase + vd0 * HW_N + j0n + vk0 * 8);
      sV1 = *(const s16x8*)(vbase + vd1 * HW_N + j0n + vk1 * 8);
      sV2 = *(const s16x8*)(vbase + vd2 * HW_N + j0n + vk2 * 8);
    }
    float rh_[4];
    {
      const int hkl = t >> 1;
#pragma unroll
      for (int r = 0; r < 4; ++r) rh_[r] = __shfl(rh_pre[r], hkl, 16);
    }
    __syncthreads();  // staged tile visible

    // ---- S = Q K^T (16q x 48k) ----
    f32x4 s0 = {}, s1 = {}, s2 = {};
#pragma unroll
    for (int kk = 0; kk < 4; ++kk) {
      const int inr = kk * 64 + g * 16;
      s16x8 b0 = *(const s16x8*)(smK + c * 256 + (inr ^ swzc));
      s16x8 b1 = *(const s16x8*)(smK + (16 + c) * 256 + (inr ^ swzc));
      s16x8 b2 = *(const s16x8*)(smK + (32 + c) * 256 + (inr ^ swzc));
      s0 = __builtin_amdgcn_mfma_f32_16x16x32_bf16(aq[kk], b0, s0, 0, 0, 0);
      s1 = __builtin_amdgcn_mfma_f32_16x16x32_bf16(aq[kk], b1, s1, 0, 0, 0);
      s2 = __builtin_amdgcn_mfma_f32_16x16x32_bf16(aq[kk], b2, s2, 0, 0, 0);
    }

    // ---- bias + online softmax with defer-max ----
    const bool par = (t & 1) != 0;
    float x0[4], x1[4], x2[4], tm3[4];
    int need = 0;
#pragma unroll
    for (int r = 0; r < 4; ++r) {
      x0[r] = s0[r] + (par ? bw1[0][r] : bw0[0][r]) + rh_[r];
      x1[r] = s1[r] + (par ? bw1[1][r] : bw0[1][r]) + rh_[r];
      x2[r] = s2[r] + (par ? bw1[2][r] : bw0[2][r]) + rh_[r];
      tm3[r] = fmaxf(fmaxf(x0[r], x1[r]), x2[r]);
      need |= (tm3[r] > mrun[r] + 8.f);
    }
    if (__any(need)) {
#pragma unroll
      for (int r = 0; r < 4; ++r) {
        float tg = tm3[r];
        tg = fmaxf(tg, __shfl_xor(tg, 1, 16));
        tg = fmaxf(tg, __shfl_xor(tg, 2, 16));
        tg = fmaxf(tg, __shfl_xor(tg, 4, 16));
        tg = fmaxf(tg, __shfl_xor(tg, 8, 16));
        float mn = fmaxf(mrun[r], tg);
        float fac = __expf(mrun[r] - mn);
        mrun[r] = mn;
        lrun[r] *= fac;
#pragma unroll
        for (int cb = 0; cb < 8; ++cb) o[cb][r] *= fac;
      }
    }
#pragma unroll
    for (int r = 0; r < 4; ++r) {
      float p0 = __expf(x0[r] - mrun[r]);
      float p1 = __expf(x1[r] - mrun[r]);
      float p2 = __expf(x2[r] - mrun[r]);
      lrun[r] += p0 + p1 + p2;
      const int q_ = g * 4 + r;
      unsigned char* prow = smP + woff + q_ * 128;
      const int swzq = ((q_ >> 2) << 5) | ((q_ & 1) << 4);
      *(unsigned short*)(prow + ((c * 2) ^ swzq)) = f2bf(p0);
      *(unsigned short*)(prow + ((32 + c * 2) ^ swzq)) = f2bf(p1);
      *(unsigned short*)(prow + ((64 + c * 2) ^ swzq)) = f2bf(p2);
    }

    // ---- O += P V ----
    s16x8 pa0 = *(const s16x8*)(smP + woff + c * 128 + ((g * 16) ^ pswz_c));
    s16x8 pa1 = *(const s16x8*)(smP + woff + c * 128 + ((64 + g * 16) ^ pswz_c));
#pragma unroll
    for (int cb = 0; cb < 8; ++cb) {
      const unsigned char* vrow = smV + (cb * 16 + c) * 128;
      s16x8 v0 = *(const s16x8*)(vrow + ((g * 16) ^ swzc));
      s16x8 v1 = *(const s16x8*)(vrow + ((64 + g * 16) ^ swzc));
      o[cb] = __builtin_amdgcn_mfma_f32_16x16x32_bf16(pa0, v0, o[cb], 0, 0, 0);
      o[cb] = __builtin_amdgcn_mfma_f32_16x16x32_bf16(pa1, v1, o[cb], 0, 0, 0);
    }
  }

  // final per-row l reduce across the 16-lane group
#pragma unroll
  for (int r = 0; r < 4; ++r) {
    lrun[r] += __shfl_xor(lrun[r], 1, 16);
    lrun[r] += __shfl_xor(lrun[r], 2, 16);
    lrun[r] += __shfl_xor(lrun[r], 4, 16);
    lrun[r] += __shfl_xor(lrun[r], 8, 16);
  }

  const int pb = (kh * 4 + h) * HW_N;
#pragma unroll
  for (int r = 0; r < 4; ++r) {
    const int p = qbase + g * 4 + r;
    unsigned short* orow = Opart + ((size_t)pb + p) * 128 + c;
#pragma unroll
    for (int cb = 0; cb < 8; ++cb) orow[cb * 16] = f2bf(o[cb][r]);
    if (c == 0) {
      mlbuf[((size_t)pb + p) * 2 + 0] = mrun[r];
      mlbuf[((size_t)pb + p) * 2 + 1] = lrun[r];
    }
  }
}

// ---------------------------------------------------------------------------
// merge 4 split-K partials -> out_att[p][512] (p-major for conv stage)
// ---------------------------------------------------------------------------
__global__ __launch_bounds__(256) void merge_kernel(
    const unsigned short* __restrict__ Opart, const float* __restrict__ mlbuf,
    float* __restrict__ oatt)
{
  int idx = (int)blockIdx.x * 256 + (int)threadIdx.x;  // 4*4608*32
  int d4 = idx & 31;
  int rest = idx >> 5;
  int p = rest % HW_N;
  int h = rest / HW_N;
  float m[4], l[4];
#pragma unroll
  for (int s = 0; s < 4; ++s) {
    int ip = (s * 4 + h) * HW_N + p;
    m[s] = mlbuf[(size_t)ip * 2];
    l[s] = mlbuf[(size_t)ip * 2 + 1];
  }
  float M = fmaxf(fmaxf(m[0], m[1]), fmaxf(m[2], m[3]));
  float a[4], den = 0.f;
#pragma unroll
  for (int s = 0; s < 4; ++s) { a[s] = __expf(m[s] - M); den += a[s] * l[s]; }
  float rd = 1.f / den;
  f32x4 acc = {};
#pragma unroll
  for (int s = 0; s < 4; ++s) {
    int ip = (s * 4 + h) * HW_N + p;
    u16x4 ov = *(const u16x4*)(Opart + (size_t)ip * 128 + d4 * 4);
#pragma unroll
    for (int j = 0; j < 4; ++j) acc[j] = fmaf(a[s], bf2f(ov[j]), acc[j]);
  }
  f32x4 res;
#pragma unroll
  for (int j = 0; j < 4; ++j) res[j] = acc[j] * rd;
  *(f32x4*)(oatt + (size_t)p * 512 + h * 128 + d4 * 4) = res;
}

// ---------------------------------------------------------------------------
// convout: fm[256][4608] = relu(bn(w_out @ out_att^T) + x); K=512
// ---------------------------------------------------------------------------
__global__ __launch_bounds__(256) void convout_kernel(
    const float* __restrict__ oatt, const float* __restrict__ w,
    const float* __restrict__ gg, const float* __restrict__ bb,
    const float* __restrict__ mm, const float* __restrict__ vv,
    const float* __restrict__ x, float* __restrict__ fm)
{
  __shared__ __align__(16) unsigned char smA[16384];
  __shared__ __align__(16) unsigned char smB[16384];
  const int tid = (int)threadIdx.x;
  const int tx = tid & 15, ty = tid >> 4;
  const int p0 = (int)blockIdx.x * 64;
  const int o0 = (int)blockIdx.y * 64;
  float acc[4][4] = {};  // [oc][p]
  for (int ch = 0; ch < 8; ++ch) {
    __syncthreads();
#pragma unroll
    for (int pass = 0; pass < 4; ++pass) {
      int c4 = tid + pass * 256;
      int oc = c4 >> 4, cc4 = c4 & 15;
      f32x4 a = *(const f32x4*)(w + (o0 + oc) * 512 + ch * 64 + cc4 * 4);
#pragma unroll
      for (int k = 0; k < 4; ++k) {
        int cc = cc4 * 4 + k;
        *(float*)(smA + cc * 256 + ((oc * 4) ^ ((cc & 7) << 4))) = a[k];
      }
      int pl = c4 >> 4, cc4b = c4 & 15;
      f32x4 b = *(const f32x4*)(oatt + (size_t)(p0 + pl) * 512 + ch * 64 + cc4b * 4);
#pragma unroll
      for (int k = 0; k < 4; ++k) {
        int cc = cc4b * 4 + k;
        *(float*)(smB + cc * 256 + ((pl * 4) ^ ((cc & 7) << 4))) = b[k];
      }
    }
    __syncthreads();
#pragma unroll 8
    for (int cc = 0; cc < 64; ++cc) {
      f32x4 av = *(const f32x4*)(smA + cc * 256 + ((ty * 16) ^ ((cc & 7) << 4)));
      f32x4 bv = *(const f32x4*)(smB + cc * 256 + ((tx * 16) ^ ((cc & 7) << 4)));
#pragma unroll
      for (int i = 0; i < 4; ++i)
#pragma unroll
        for (int j = 0; j < 4; ++j) acc[i][j] = fmaf(av[i], bv[j], acc[i][j]);
    }
  }
#pragma unroll
  for (int i = 0; i < 4; ++i) {
    int oc = o0 + ty * 4 + i;
    float inv = gg[oc] * rsqrtf(vv[oc] + EPS);
    float bia = bb[oc] - mm[oc] * inv;
    f32x4 xr = *(const f32x4*)(x + (size_t)oc * HW_N + p0 + tx * 4);
    f32x4 o;
#pragma unroll
    for (int j = 0; j < 4; ++j) o[j] = fmaxf(acc[i][j] * inv + bia + xr[j], 0.f);
    *(f32x4*)(fm + (size_t)oc * HW_N + p0 + tx * 4) = o;
  }
}

// ---------------------------------------------------------------------------
// convhead: out[19][4608] = w_head @ fm + b_head; K=256
// ---------------------------------------------------------------------------
__global__ __launch_bounds__(256) void convhead_kernel(
    const float* __restrict__ fm, const float* __restrict__ w,
    const float* __restrict__ bh, float* __restrict__ outp)
{
  __shared__ __align__(16) unsigned char smA[16384];
  __shared__ __align__(16) unsigned char smB[16384];
  const int tid = (int)threadIdx.x;
  const int tx = tid & 15, ty = tid >> 4;
  const int p0 = (int)blockIdx.x * 64;
  float acc[4][4] = {};
  for (int ch = 0; ch < 4; ++ch) {
    __syncthreads();
#pragma unroll
    for (int pass = 0; pass < 4; ++pass) {
      int c4 = tid + pass * 256;
      int oc = c4 >> 4, cc4 = c4 & 15;
      f32x4 a = {};
      if (oc < 19) a = *(const f32x4*)(w + oc * 256 + ch * 64 + cc4 * 4);
#pragma unroll
      for (int k = 0; k < 4; ++k) {
        int cc = cc4 * 4 + k;
        *(float*)(smA + cc * 256 + ((oc * 4) ^ ((cc & 7) << 4))) = a[k];
      }
      int cc = c4 >> 4, pp4 = c4 & 15;
      f32x4 b = *(const f32x4*)(fm + (ch * 64 + cc) * HW_N + p0 + pp4 * 4);
      *(f32x4*)(smB + cc * 256 + ((pp4 * 16) ^ ((cc & 7) << 4))) = b;
    }
    __syncthreads();
#pragma unroll 8
    for (int cc = 0; cc < 64; ++cc) {
      f32x4 av = *(const f32x4*)(smA + cc * 256 + ((ty * 16) ^ ((cc & 7) << 4)));
      f32x4 bv = *(const f32x4*)(smB + cc * 256 + ((tx * 16) ^ ((cc & 7) << 4)));
#pragma unroll
      for (int i = 0; i < 4; ++i)
#pragma unroll
        for (int j = 0; j < 4; ++j) acc[i][j] = fmaf(av[i], bv[j], acc[i][j]);
    }
  }
#pragma unroll
  for (int i = 0; i < 4; ++i) {
    int oc = ty * 4 + i;
    if (oc < 19) {
      f32x4 o;
#pragma unroll
      for (int j = 0; j < 4; ++j) o[j] = acc[i][j] + bh[oc];
      *(f32x4*)(outp + oc * HW_N + p0 + tx * 4) = o;
    }
  }
}

// ---------------------------------------------------------------------------
extern "C" void kernel_launch(void* const* d_in, const int* in_sizes, int n_in,
                              void* d_out, int out_size, void* d_ws, size_t ws_size,
                              hipStream_t stream)
{
  const float* x     = (const float*)d_in[0];
  const float* w_in  = (const float*)d_in[1];
  const float* bn1_g = (const float*)d_in[2];
  const float* bn1_b = (const float*)d_in[3];
  const float* bn1_m = (const float*)d_in[4];
  const float* bn1_v = (const float*)d_in[5];
  const float* w_qkv = (const float*)d_in[6];
  const float* rel_h = (const float*)d_in[7];
  const float* rel_w = (const float*)d_in[8];
  const float* w_out = (const float*)d_in[9];
  const float* bn2_g = (const float*)d_in[10];
  const float* bn2_b = (const float*)d_in[11];
  const float* bn2_m = (const float*)d_in[12];
  const float* bn2_v = (const float*)d_in[13];
  const float* w_hd  = (const float*)d_in[14];
  const float* b_hd  = (const float*)d_in[15];

  char* ws = (char*)d_ws;
  float*          h1    = (float*)(ws + 0);                   // 1,179,648 B
  float*          mlb   = (float*)(ws + 0);                   // 589,824 B (after h1 dead)
  unsigned short* qb    = (unsigned short*)(ws + 1179648);    // 4,718,592 B
  unsigned short* kb    = (unsigned short*)(ws + 5898240);    // 4,718,592 B
  unsigned short* vb    = (unsigned short*)(ws + 10616832);   // 4,718,592 B
  float*          RW    = (float*)(ws + 15335424);            // 7,077,888 B
  float*          RH    = (float*)(ws + 22413312);            // 3,538,944 B
  unsigned short* Opart = (unsigned short*)(ws + 25952256);   // 18,874,368 B (16 partials, bf16)
  float*          oatt  = (float*)(ws + 45121536);            // 9,437,184 B
  float*          fm    = (float*)(ws + 54558720);            // 4,718,592 B

  conv1_kernel<<<72, 256, 0, stream>>>(x, w_in, bn1_g, bn1_b, bn1_m, bn1_v, h1);
  convqkv_kernel<<<dim3(72, 24), 256, 0, stream>>>(h1, w_qkv, qb, kb, vb);
  relpre_mfma<<<dim3(96, 4), 256, 0, stream>>>(qb, rel_w, RW, 0);
  relpre_mfma<<<dim3(48, 4), 256, 0, stream>>>(qb, rel_h, RH, 1);
  attn_kernel<<<dim3(72, 4, 4), 256, 0, stream>>>(qb, kb, vb, RW, RH, Opart, mlb);
  merge_kernel<<<2304, 256, 0, stream>>>(Opart, mlb, oatt);
  convout_kernel<<<dim3(72, 4), 256, 0, stream>>>(oatt, w_out, bn2_g, bn2_b, bn2_m,
                                                  bn2_v, x, fm);
  convhead_kernel<<<72, 256, 0, stream>>>(fm, w_hd, b_hd, (float*)d_out);
}